// Round 2
// baseline (161.744 us; speedup 1.0000x reference)
//
#include <hip/hip_runtime.h>

// ---------------------------------------------------------------------------
// DotProductAttention: out[b,i,f] = softmax_j(<K_i, Q_j>) @ V[j,f]
// Split-bf16 (hi+lo) path: scores fp32-accurate; V single bf16.
// B=8, L=4096, F=64.
// ---------------------------------------------------------------------------

typedef unsigned short u16;
typedef __attribute__((ext_vector_type(4))) u16 u16x4;
typedef __attribute__((ext_vector_type(4))) unsigned int u32x4;
typedef __attribute__((ext_vector_type(4))) float f32x4;
typedef __attribute__((ext_vector_type(4))) short s16x4;
typedef __attribute__((ext_vector_type(8))) short s16x8;

#define MFMA16(a, bb, c) __builtin_amdgcn_mfma_f32_16x16x32_bf16((a), (bb), (c), 0, 0, 0)

__device__ __forceinline__ short f2bf(float x) {
    unsigned u = __builtin_bit_cast(unsigned, x);
    u += 0x7fffu + ((u >> 16) & 1u);   // round-to-nearest-even
    return (short)(u >> 16);
}
__device__ __forceinline__ float bf2f(short h) {
    unsigned u = ((unsigned)(u16)h) << 16;
    return __builtin_bit_cast(float, u);
}

__device__ __forceinline__ f32x4 zero4() { f32x4 r = {0.f, 0.f, 0.f, 0.f}; return r; }

__device__ __forceinline__ s16x8 cat8s(s16x4 a, s16x4 b) {
    s16x8 r;
    r[0] = a[0]; r[1] = a[1]; r[2] = a[2]; r[3] = a[3];
    r[4] = b[0]; r[5] = b[1]; r[6] = b[2]; r[7] = b[3];
    return r;
}
__device__ __forceinline__ s16x8 cat8u(u16x4 a, u16x4 b) {
    s16x8 r;
    r[0] = (short)a[0]; r[1] = (short)a[1]; r[2] = (short)a[2]; r[3] = (short)a[3];
    r[4] = (short)b[0]; r[5] = (short)b[1]; r[6] = (short)b[2]; r[7] = (short)b[3];
    return r;
}

// split 8 fp32 values into hi/lo bf16 fragments
__device__ __forceinline__ void split8(f32x4 a, f32x4 b, s16x8& hi, s16x8& lo) {
#pragma unroll
    for (int i = 0; i < 4; i++) {
        short h = f2bf(a[i]);
        hi[i] = h;
        lo[i] = f2bf(a[i] - bf2f(h));
    }
#pragma unroll
    for (int i = 0; i < 4; i++) {
        short h = f2bf(b[i]);
        hi[i + 4] = h;
        lo[i + 4] = f2bf(b[i] - bf2f(h));
    }
}

// ---------------------------------------------------------------------------
// Projection kernel: Xp = X @ W^T + b, split-bf16 accurate, outputs:
//   z==0 (Q): hi+lo planes, 64-row chunks, XOR-swizzled  byte ^= (row&7)<<4
//   z==1 (K): hi+lo planes, plain row-major [32768][64]
//   z==2 (V): single bf16, 64-row chunks, TRANSPOSED ([f][j]) + swizzled on f
// grid (512, 3), block 256.
// ---------------------------------------------------------------------------
__global__ __launch_bounds__(256) void proj_qkv_32727650796335(
    const float* __restrict__ q_, const float* __restrict__ k_, const float* __restrict__ v_,
    const float* __restrict__ wq, const float* __restrict__ bq,
    const float* __restrict__ wk, const float* __restrict__ bk,
    const float* __restrict__ wv, const float* __restrict__ bv,
    u16* __restrict__ qph, u16* __restrict__ qpl,
    u16* __restrict__ kph, u16* __restrict__ kpl,
    u16* __restrict__ vp) {
    const int z = blockIdx.y;
    const float* X  = (z == 0) ? q_ : (z == 1) ? k_ : v_;
    const float* W  = (z == 0) ? wq : (z == 1) ? wk : wv;
    const float* bi = (z == 0) ? bq : (z == 1) ? bk : bv;

    const int t = threadIdx.x;
    const int w = t >> 6, ln = t & 63, g = ln >> 4, lq = ln & 15;
    const int cidx = blockIdx.x;                 // 0..511 (b*64 + chunk)

    __shared__ f32x4 ldsX[1024];                 // 64 rows x 16 float4, swizzled

    const f32x4* X4 = (const f32x4*)X + (size_t)cidx * 1024;
#pragma unroll
    for (int kk = 0; kk < 4; kk++) {
        int lin = t + 256 * kk;
        int r = lin >> 4, c4 = lin & 15;
        ldsX[r * 16 + (c4 ^ (r & 7))] = X4[lin];
    }
    __syncthreads();

    float bv4[4];
#pragma unroll
    for (int nt = 0; nt < 4; nt++) bv4[nt] = bi[lq + 16 * nt];

    // B operand = W^T split: slot(g,e) <- W[f_out = lq+16nt][f_in = 4g+e(+16h+32kb)]
    const f32x4* W4 = (const f32x4*)W;
    s16x8 wfh[4][2], wfl[4][2];
#pragma unroll
    for (int nt = 0; nt < 4; nt++)
#pragma unroll
        for (int kb = 0; kb < 2; kb++) {
            f32x4 a = W4[(lq + 16 * nt) * 16 + (g + 8 * kb)];
            f32x4 b = W4[(lq + 16 * nt) * 16 + (g + 4 + 8 * kb)];
            split8(a, b, wfh[nt][kb], wfl[nt][kb]);
        }

    // A operand = X rows split
    s16x8 afh[2], afl[2];
#pragma unroll
    for (int kb = 0; kb < 2; kb++) {
        f32x4 a = ldsX[(16 * w + lq) * 16 + ((g + 8 * kb) ^ (lq & 7))];
        f32x4 b = ldsX[(16 * w + lq) * 16 + ((g + 4 + 8 * kb) ^ (lq & 7))];
        split8(a, b, afh[kb], afl[kb]);
    }

    f32x4 acc[4];
#pragma unroll
    for (int nt = 0; nt < 4; nt++) acc[nt] = zero4();
#pragma unroll
    for (int kb = 0; kb < 2; kb++)
#pragma unroll
        for (int nt = 0; nt < 4; nt++) {
            acc[nt] = MFMA16(afh[kb], wfh[nt][kb], acc[nt]);
            acc[nt] = MFMA16(afh[kb], wfl[nt][kb], acc[nt]);
            acc[nt] = MFMA16(afl[kb], wfh[nt][kb], acc[nt]);
        }

    // D: row_local = 16w + 4g + r, col f = lq + 16nt  (C/D layout, m89/m91)
#pragma unroll
    for (int nt = 0; nt < 4; nt++)
#pragma unroll
        for (int r = 0; r < 4; r++) {
            float val = acc[nt][r] + bv4[nt];
            short hi = f2bf(val);
            short lo = f2bf(val - bf2f(hi));
            int row = 16 * w + 4 * g + r;
            int f = lq + 16 * nt;
            if (z == 1) {
                size_t idx = ((size_t)cidx * 64 + row) * 64 + f;
                kph[idx] = (u16)hi;
                kpl[idx] = (u16)lo;
            } else if (z == 0) {
                unsigned off = (unsigned)(row * 128 + ((f * 2) ^ ((row & 7) << 4)));
                size_t idx = (size_t)cidx * 4096 + (off >> 1);
                qph[idx] = (u16)hi;
                qpl[idx] = (u16)lo;
            } else {
                unsigned off = (unsigned)(f * 128 + ((row * 2) ^ ((f & 7) << 4)));
                vp[(size_t)cidx * 4096 + (off >> 1)] = (u16)hi;
            }
        }
}

// ---------------------------------------------------------------------------
// Attention kernel. grid (64 itiles, 8 batches), block 256 (4 waves).
// Swapped MFMA: S^T[j,i] tiles; lane holds i = lane&15, 16 j values.
// QK^T per tile = 3-term split (hi*hi + hi*lo + lo*hi), fp32-accurate scores.
// ---------------------------------------------------------------------------
__global__ __launch_bounds__(256, 2) void attn_fwd_32727650796335(
    const u16* __restrict__ qph, const u16* __restrict__ qpl,
    const u16* __restrict__ kph, const u16* __restrict__ kpl,
    const u16* __restrict__ vp, float* __restrict__ out) {
    const int t = threadIdx.x;
    const int w = t >> 6, ln = t & 63, g = ln >> 4, lq = ln & 15;
    const int itile = blockIdx.x, b = blockIdx.y;

    __shared__ u32x4 ldsbuf[1536];               // Qhi [0,8K), Qlo [8K,16K), V [16K,24K)
    u16* lds = (u16*)ldsbuf;

    // K fragments: slot(g,e) <- K[i = lq][f = 4g+e+16h+32kb], hi and lo planes
    const int irow = (b * 64 + itile) * 64 + 16 * w + lq;   // global LK row
    const size_t koff = (size_t)irow * 64 + 4 * g;
    const u16* krh = kph + koff;
    const u16* krl = kpl + koff;
    s16x8 kf0h = cat8u(*(const u16x4*)(krh),      *(const u16x4*)(krh + 16));
    s16x8 kf1h = cat8u(*(const u16x4*)(krh + 32), *(const u16x4*)(krh + 48));
    s16x8 kf0l = cat8u(*(const u16x4*)(krl),      *(const u16x4*)(krl + 16));
    s16x8 kf1l = cat8u(*(const u16x4*)(krl + 32), *(const u16x4*)(krl + 48));

    f32x4 oacc[4];
#pragma unroll
    for (int ft = 0; ft < 4; ft++) oacc[ft] = zero4();
    float m = -__builtin_inff();
    float lsum = 0.f;

    const unsigned sw = (unsigned)((lq & 7) << 4);
    const unsigned rbase = (unsigned)(lq * 128) + ((unsigned)(8 * g) ^ sw);

    const u32x4* qsrcH = (const u32x4*)(qph + (size_t)(b * 64) * 4096);
    const u32x4* qsrcL = (const u32x4*)(qpl + (size_t)(b * 64) * 4096);
    const u32x4* vsrc  = (const u32x4*)(vp  + (size_t)(b * 64) * 4096);

    for (int c = 0; c < 64; c++) {
        u32x4 qha = qsrcH[c * 512 + t];
        u32x4 qhb = qsrcH[c * 512 + t + 256];
        u32x4 qla = qsrcL[c * 512 + t];
        u32x4 qlb = qsrcL[c * 512 + t + 256];
        u32x4 va  = vsrc[c * 512 + t];
        u32x4 vb  = vsrc[c * 512 + t + 256];
        __syncthreads();
        ldsbuf[t] = qha;
        ldsbuf[t + 256] = qhb;
        ldsbuf[t + 512] = qla;
        ldsbuf[t + 768] = qlb;
        ldsbuf[t + 1024] = va;
        ldsbuf[t + 1280] = vb;
        __syncthreads();

        // ---- QK^T : S^T tiles (M=j 16, N=i 16, K=64), split-bf16 ----
        f32x4 s[4];
#pragma unroll
        for (int t4 = 0; t4 < 4; t4++) {
            unsigned base = rbase + (unsigned)(t4 * 2048);
            s16x4 h00 = *(const s16x4*)((const char*)lds + base);
            s16x4 h01 = *(const s16x4*)((const char*)lds + (base ^ 32u));
            s16x4 h10 = *(const s16x4*)((const char*)lds + (base ^ 64u));
            s16x4 h11 = *(const s16x4*)((const char*)lds + (base ^ 96u));
            s16x4 l00 = *(const s16x4*)((const char*)lds + 8192 + base);
            s16x4 l01 = *(const s16x4*)((const char*)lds + 8192 + (base ^ 32u));
            s16x4 l10 = *(const s16x4*)((const char*)lds + 8192 + (base ^ 64u));
            s16x4 l11 = *(const s16x4*)((const char*)lds + 8192 + (base ^ 96u));
            s16x8 ah0 = cat8s(h00, h01), ah1 = cat8s(h10, h11);
            s16x8 al0 = cat8s(l00, l01), al1 = cat8s(l10, l11);
            f32x4 acc = zero4();
            acc = MFMA16(ah0, kf0h, acc);
            acc = MFMA16(ah1, kf1h, acc);
            acc = MFMA16(ah0, kf0l, acc);
            acc = MFMA16(ah1, kf1l, acc);
            acc = MFMA16(al0, kf0h, acc);
            acc = MFMA16(al1, kf1h, acc);
            s[t4] = acc;
        }

        // ---- online softmax over j ----
        float pmax = s[0][0];
#pragma unroll
        for (int t4 = 0; t4 < 4; t4++)
#pragma unroll
            for (int r = 0; r < 4; r++) pmax = fmaxf(pmax, s[t4][r]);
        pmax = fmaxf(pmax, __shfl_xor(pmax, 16));
        pmax = fmaxf(pmax, __shfl_xor(pmax, 32));
        float mnew = fmaxf(m, pmax);
        float corr = __expf(m - mnew);

        // P rounded to bf16; lsum accumulated from ROUNDED values (consistency)
        s16x8 pb0, pb1;
        float psum = 0.f;
#pragma unroll
        for (int r = 0; r < 4; r++) {
            short h0 = f2bf(__expf(s[0][r] - mnew));
            short h1 = f2bf(__expf(s[1][r] - mnew));
            short h2 = f2bf(__expf(s[2][r] - mnew));
            short h3 = f2bf(__expf(s[3][r] - mnew));
            pb0[r] = h0; pb0[r + 4] = h1;
            pb1[r] = h2; pb1[r + 4] = h3;
            psum += bf2f(h0) + bf2f(h1) + bf2f(h2) + bf2f(h3);
        }
        psum += __shfl_xor(psum, 16);
        psum += __shfl_xor(psum, 32);
        lsum = lsum * corr + psum;
        m = mnew;
#pragma unroll
        for (int ft = 0; ft < 4; ft++) oacc[ft] *= corr;

        // ---- PV : O^T[f,i] += V^T @ P^T ----
#pragma unroll
        for (int ft = 0; ft < 4; ft++) {
            unsigned base = rbase + (unsigned)(16384 + ft * 2048);
            s16x4 v00 = *(const s16x4*)((const char*)lds + base);
            s16x4 v01 = *(const s16x4*)((const char*)lds + (base ^ 32u));
            s16x4 v10 = *(const s16x4*)((const char*)lds + (base ^ 64u));
            s16x4 v11 = *(const s16x4*)((const char*)lds + (base ^ 96u));
            oacc[ft] = MFMA16(cat8s(v00, v01), pb0, oacc[ft]);
            oacc[ft] = MFMA16(cat8s(v10, v11), pb1, oacc[ft]);
        }
    }

    // ---- epilogue: out[b, irow, f] = O^T[f, i]/lsum ; f = 16ft + 4g + r ----
    float inv = 1.f / lsum;
#pragma unroll
    for (int ft = 0; ft < 4; ft++) {
        f32x4 o = oacc[ft] * inv;
        *(f32x4*)(out + (size_t)irow * 64 + 16 * ft + 4 * g) = o;
    }
}

// ---------------------------------------------------------------------------
extern "C" void kernel_launch(void* const* d_in, const int* in_sizes, int n_in,
                              void* d_out, int out_size, void* d_ws, size_t ws_size,
                              hipStream_t stream) {
    (void)in_sizes; (void)n_in; (void)out_size; (void)ws_size;
    const float* q_ = (const float*)d_in[0];
    const float* k_ = (const float*)d_in[1];
    const float* v_ = (const float*)d_in[2];
    const float* wq = (const float*)d_in[3];
    const float* bq = (const float*)d_in[4];
    const float* wk = (const float*)d_in[5];
    const float* bk = (const float*)d_in[6];
    const float* wv = (const float*)d_in[7];
    const float* bv = (const float*)d_in[8];

    const size_t PLANE = (size_t)8 * 4096 * 64;   // 2M elements (4 MB bf16)
    u16* qph = (u16*)d_ws;
    u16* qpl = qph + PLANE;
    u16* kph = qpl + PLANE;
    u16* kpl = kph + PLANE;
    u16* vp  = kpl + PLANE;

    proj_qkv_32727650796335<<<dim3(512, 3, 1), 256, 0, stream>>>(
        q_, k_, v_, wq, bq, wk, bk, wv, bv, qph, qpl, kph, kpl, vp);
    attn_fwd_32727650796335<<<dim3(64, 8, 1), 256, 0, stream>>>(
        qph, qpl, kph, kpl, vp, (float*)d_out);
}

// Round 3
// 150.676 us; speedup vs baseline: 1.0735x; 1.0735x over previous
//
#include <hip/hip_runtime.h>

// ---------------------------------------------------------------------------
// DotProductAttention: out[b,i,f] = softmax_j(<K_i, Q_j>) @ V[j,f]
// Split-bf16 (hi+lo) scores; flash-decoding j-split for occupancy.
// B=8, L=4096, F=64.
// ---------------------------------------------------------------------------

typedef unsigned short u16;
typedef __attribute__((ext_vector_type(4))) u16 u16x4;
typedef __attribute__((ext_vector_type(4))) unsigned int u32x4;
typedef __attribute__((ext_vector_type(4))) float f32x4;
typedef __attribute__((ext_vector_type(2))) float f32x2;
typedef __attribute__((ext_vector_type(4))) short s16x4;
typedef __attribute__((ext_vector_type(8))) short s16x8;

#define MFMA16(a, bb, c) __builtin_amdgcn_mfma_f32_16x16x32_bf16((a), (bb), (c), 0, 0, 0)

__device__ __forceinline__ short f2bf(float x) {
    unsigned u = __builtin_bit_cast(unsigned, x);
    u += 0x7fffu + ((u >> 16) & 1u);   // round-to-nearest-even
    return (short)(u >> 16);
}
__device__ __forceinline__ float bf2f(short h) {
    unsigned u = ((unsigned)(u16)h) << 16;
    return __builtin_bit_cast(float, u);
}

__device__ __forceinline__ f32x4 zero4() { f32x4 r = {0.f, 0.f, 0.f, 0.f}; return r; }

__device__ __forceinline__ s16x8 cat8s(s16x4 a, s16x4 b) {
    s16x8 r;
    r[0] = a[0]; r[1] = a[1]; r[2] = a[2]; r[3] = a[3];
    r[4] = b[0]; r[5] = b[1]; r[6] = b[2]; r[7] = b[3];
    return r;
}

// split 8 fp32 values into hi/lo bf16 fragments
__device__ __forceinline__ void split8(f32x4 a, f32x4 b, s16x8& hi, s16x8& lo) {
#pragma unroll
    for (int i = 0; i < 4; i++) {
        short h = f2bf(a[i]);
        hi[i] = h;
        lo[i] = f2bf(a[i] - bf2f(h));
    }
#pragma unroll
    for (int i = 0; i < 4; i++) {
        short h = f2bf(b[i]);
        hi[i + 4] = h;
        lo[i + 4] = f2bf(b[i] - bf2f(h));
    }
}

// ---------------------------------------------------------------------------
// Projection kernel: Xp = X @ W^T + b, split-bf16 accurate, outputs:
//   z==0 (Q): hi+lo planes, 64-row chunks, 16B-unit swizzle: u = (f>>3)^(row&7)
//   z==1 (K): hi+lo planes, plain row-major [32768][64]
//   z==2 (V): single bf16, 64-row chunks, TRANSPOSED ([f][j]) + swizzled on f
// grid (512, 3), block 256.
// ---------------------------------------------------------------------------
__global__ __launch_bounds__(256) void proj_qkv_32727650796335(
    const float* __restrict__ q_, const float* __restrict__ k_, const float* __restrict__ v_,
    const float* __restrict__ wq, const float* __restrict__ bq,
    const float* __restrict__ wk, const float* __restrict__ bk,
    const float* __restrict__ wv, const float* __restrict__ bv,
    u16* __restrict__ qph, u16* __restrict__ qpl,
    u16* __restrict__ kph, u16* __restrict__ kpl,
    u16* __restrict__ vp) {
    const int z = blockIdx.y;
    const float* X  = (z == 0) ? q_ : (z == 1) ? k_ : v_;
    const float* W  = (z == 0) ? wq : (z == 1) ? wk : wv;
    const float* bi = (z == 0) ? bq : (z == 1) ? bk : bv;

    const int t = threadIdx.x;
    const int w = t >> 6, ln = t & 63, g = ln >> 4, lq = ln & 15;
    const int cidx = blockIdx.x;                 // 0..511 (b*64 + chunk)

    __shared__ f32x4 ldsX[1024];                 // 64 rows x 16 float4, swizzled

    const f32x4* X4 = (const f32x4*)X + (size_t)cidx * 1024;
#pragma unroll
    for (int kk = 0; kk < 4; kk++) {
        int lin = t + 256 * kk;
        int r = lin >> 4, c4 = lin & 15;
        ldsX[r * 16 + (c4 ^ (r & 7))] = X4[lin];
    }
    __syncthreads();

    float bv4[4];
#pragma unroll
    for (int nt = 0; nt < 4; nt++) bv4[nt] = bi[lq + 16 * nt];

    // B operand = W^T split: slot(g,e) <- W[f_out = lq+16nt][f_in = 4g+e(+16h+32kb)]
    const f32x4* W4 = (const f32x4*)W;
    s16x8 wfh[4][2], wfl[4][2];
#pragma unroll
    for (int nt = 0; nt < 4; nt++)
#pragma unroll
        for (int kb = 0; kb < 2; kb++) {
            f32x4 a = W4[(lq + 16 * nt) * 16 + (g + 8 * kb)];
            f32x4 b = W4[(lq + 16 * nt) * 16 + (g + 4 + 8 * kb)];
            split8(a, b, wfh[nt][kb], wfl[nt][kb]);
        }

    // A operand = X rows split
    s16x8 afh[2], afl[2];
#pragma unroll
    for (int kb = 0; kb < 2; kb++) {
        f32x4 a = ldsX[(16 * w + lq) * 16 + ((g + 8 * kb) ^ (lq & 7))];
        f32x4 b = ldsX[(16 * w + lq) * 16 + ((g + 4 + 8 * kb) ^ (lq & 7))];
        split8(a, b, afh[kb], afl[kb]);
    }

    f32x4 acc[4];
#pragma unroll
    for (int nt = 0; nt < 4; nt++) acc[nt] = zero4();
#pragma unroll
    for (int kb = 0; kb < 2; kb++)
#pragma unroll
        for (int nt = 0; nt < 4; nt++) {
            acc[nt] = MFMA16(afh[kb], wfh[nt][kb], acc[nt]);
            acc[nt] = MFMA16(afh[kb], wfl[nt][kb], acc[nt]);
            acc[nt] = MFMA16(afl[kb], wfh[nt][kb], acc[nt]);
        }

    // D: row_local = 16w + 4g + r, col f = lq + 16nt  (C/D layout, m89/m91)
#pragma unroll
    for (int nt = 0; nt < 4; nt++)
#pragma unroll
        for (int r = 0; r < 4; r++) {
            float val = acc[nt][r] + bv4[nt];
            short hi = f2bf(val);
            short lo = f2bf(val - bf2f(hi));
            int row = 16 * w + 4 * g + r;
            int f = lq + 16 * nt;
            if (z == 1) {
                size_t idx = ((size_t)cidx * 64 + row) * 64 + f;
                kph[idx] = (u16)hi;
                kpl[idx] = (u16)lo;
            } else if (z == 0) {
                // unit-swizzled row-major: u16 idx = row*64 + ((f>>3)^(row&7))*8 + (f&7)
                unsigned idx = (unsigned)(row * 64 + ((((f >> 3) ^ (row & 7)) << 3) | (f & 7)));
                size_t o = (size_t)cidx * 4096 + idx;
                qph[o] = (u16)hi;
                qpl[o] = (u16)lo;
            } else {
                unsigned off = (unsigned)(f * 128 + ((row * 2) ^ ((f & 7) << 4)));
                vp[(size_t)cidx * 4096 + (off >> 1)] = (u16)hi;
            }
        }
}

// ---------------------------------------------------------------------------
// Attention kernel. grid (64 itiles, 8 batches, nsplit). block 256 (4 waves).
// Each z-split handles nc = 64/nsplit chunks of j; writes partial (O, m, l)
// unless nsplit==1 (writes normalized out directly).
// ---------------------------------------------------------------------------
__global__ __launch_bounds__(256, 4) void attn_fwd_32727650796335(
    const u16* __restrict__ qph, const u16* __restrict__ qpl,
    const u16* __restrict__ kph, const u16* __restrict__ kpl,
    const u16* __restrict__ vp, float* __restrict__ out,
    float* __restrict__ pO, f32x2* __restrict__ pML, int nsplit) {
    const int t = threadIdx.x;
    const int w = t >> 6, ln = t & 63, g = ln >> 4, lq = ln & 15;
    const int itile = blockIdx.x, b = blockIdx.y, split = blockIdx.z;
    const int nc = 64 / nsplit;
    const int c0 = split * nc;

    __shared__ u32x4 ldsbuf[1536];               // Qhi [0,8K), Qlo [8K,16K), V [16K,24K)
    u16* lds = (u16*)ldsbuf;

    // K fragments, contiguous k-map for QK^T: slot(g,e) <- k = 16g+e (+8 for kf1)
    const int irow = (b * 64 + itile) * 64 + 16 * w + lq;   // global LK row
    const u16* krh = kph + (size_t)irow * 64;
    const u16* krl = kpl + (size_t)irow * 64;
    s16x8 kf0h = *(const s16x8*)(krh + 16 * g);
    s16x8 kf1h = *(const s16x8*)(krh + 16 * g + 8);
    s16x8 kf0l = *(const s16x8*)(krl + 16 * g);
    s16x8 kf1l = *(const s16x8*)(krl + 16 * g + 8);

    f32x4 oacc[4];
#pragma unroll
    for (int ft = 0; ft < 4; ft++) oacc[ft] = zero4();
    float m = -__builtin_inff();
    float lsum = 0.f;

    const unsigned sw7 = (unsigned)(lq & 7);
    const unsigned qrowb = (unsigned)(lq * 128);
    const unsigned u0 = (unsigned)(2 * g) ^ sw7;           // Q 16B-unit, half 0
    const unsigned u1 = (unsigned)(2 * g + 1) ^ sw7;       // Q 16B-unit, half 1
    // PV (old map) read base into V region:
    const unsigned vrbase = qrowb + (((unsigned)(8 * g)) ^ (sw7 << 4));

    const u32x4* qsrcH = (const u32x4*)(qph + (size_t)(b * 64) * 4096);
    const u32x4* qsrcL = (const u32x4*)(qpl + (size_t)(b * 64) * 4096);
    const u32x4* vsrc  = (const u32x4*)(vp  + (size_t)(b * 64) * 4096);

    u32x4 qha, qhb, qla, qlb, va, vb;
#define LOADC(c) do { size_t o_ = (size_t)(c) * 512 + t;      \
        qha = qsrcH[o_]; qhb = qsrcH[o_ + 256];               \
        qla = qsrcL[o_]; qlb = qsrcL[o_ + 256];               \
        va  = vsrc[o_];  vb  = vsrc[o_ + 256]; } while (0)

    LOADC(c0);
    for (int cc = 0; cc < nc; cc++) {
        __syncthreads();                          // prev iter done reading LDS
        ldsbuf[t] = qha;
        ldsbuf[t + 256] = qhb;
        ldsbuf[t + 512] = qla;
        ldsbuf[t + 768] = qlb;
        ldsbuf[t + 1024] = va;
        ldsbuf[t + 1280] = vb;
        __syncthreads();
        if (cc + 1 < nc) LOADC(c0 + cc + 1);      // prefetch next chunk under compute

        // ---- QK^T : S^T tiles (M=j 16, N=i 16, K=64), split-bf16, b128 reads ----
        f32x4 s[4];
#pragma unroll
        for (int t4 = 0; t4 < 4; t4++) {
            const char* pb = (const char*)lds + t4 * 2048 + qrowb;
            s16x8 qh0 = *(const s16x8*)(pb + (u0 << 4));
            s16x8 qh1 = *(const s16x8*)(pb + (u1 << 4));
            s16x8 ql0 = *(const s16x8*)(pb + 8192 + (u0 << 4));
            s16x8 ql1 = *(const s16x8*)(pb + 8192 + (u1 << 4));
            f32x4 acc = zero4();
            acc = MFMA16(qh0, kf0h, acc);
            acc = MFMA16(qh1, kf1h, acc);
            acc = MFMA16(qh0, kf0l, acc);
            acc = MFMA16(qh1, kf1l, acc);
            acc = MFMA16(ql0, kf0h, acc);
            acc = MFMA16(ql1, kf1h, acc);
            s[t4] = acc;
        }

        // ---- online softmax over j ----
        float pmax = s[0][0];
#pragma unroll
        for (int t4 = 0; t4 < 4; t4++)
#pragma unroll
            for (int r = 0; r < 4; r++) pmax = fmaxf(pmax, s[t4][r]);
        pmax = fmaxf(pmax, __shfl_xor(pmax, 16));
        pmax = fmaxf(pmax, __shfl_xor(pmax, 32));
        if (!__all(pmax <= m)) {                  // T13: skip rescale when max unchanged
            float mnew = fmaxf(m, pmax);
            float corr = __expf(m - mnew);        // first chunk: exp(-inf)=0
            lsum *= corr;
#pragma unroll
            for (int ft = 0; ft < 4; ft++) oacc[ft] *= corr;
            m = mnew;
        }

        s16x8 pb0, pb1;
        float psum = 0.f;
#pragma unroll
        for (int r = 0; r < 4; r++) {
            float e0 = __expf(s[0][r] - m);
            float e1 = __expf(s[1][r] - m);
            float e2 = __expf(s[2][r] - m);
            float e3 = __expf(s[3][r] - m);
            psum += (e0 + e1) + (e2 + e3);
            pb0[r] = f2bf(e0); pb0[r + 4] = f2bf(e1);
            pb1[r] = f2bf(e2); pb1[r + 4] = f2bf(e3);
        }
        psum += __shfl_xor(psum, 16);
        psum += __shfl_xor(psum, 32);
        lsum += psum;

        // ---- PV : O^T[f,i] += V^T @ P^T  (old interleaved k-map, P lane-local) ----
#pragma unroll
        for (int ft = 0; ft < 4; ft++) {
            unsigned base = vrbase + (unsigned)(16384 + ft * 2048);
            s16x4 v00 = *(const s16x4*)((const char*)lds + base);
            s16x4 v01 = *(const s16x4*)((const char*)lds + (base ^ 32u));
            s16x4 v10 = *(const s16x4*)((const char*)lds + (base ^ 64u));
            s16x4 v11 = *(const s16x4*)((const char*)lds + (base ^ 96u));
            oacc[ft] = MFMA16(cat8s(v00, v01), pb0, oacc[ft]);
            oacc[ft] = MFMA16(cat8s(v10, v11), pb1, oacc[ft]);
        }
    }
#undef LOADC

    // ---- epilogue ----
    if (nsplit == 1) {
        float inv = 1.f / lsum;
#pragma unroll
        for (int ft = 0; ft < 4; ft++) {
            f32x4 o = oacc[ft] * inv;
            *(f32x4*)(out + (size_t)irow * 64 + 16 * ft + 4 * g) = o;
        }
    } else {
        size_t base = (size_t)split * 32768 + (size_t)irow;
#pragma unroll
        for (int ft = 0; ft < 4; ft++) {
            *(f32x4*)(pO + base * 64 + 16 * ft + 4 * g) = oacc[ft];
        }
        if (g == 0) {
            f32x2 ml; ml[0] = m; ml[1] = lsum;
            pML[base] = ml;
        }
    }
}

// ---------------------------------------------------------------------------
// Combine kernel: merge nsplit partials. grid 512 (b*64+itile), block 256.
// thread t: row = t>>2 (0..63), f-quarter = (t&3)*16.
// ---------------------------------------------------------------------------
__global__ __launch_bounds__(256) void combine_32727650796335(
    const float* __restrict__ pO, const f32x2* __restrict__ pML,
    float* __restrict__ out, int nsplit) {
    const int bt = blockIdx.x;
    const int t = threadIdx.x;
    const int row = t >> 2, fb = (t & 3) << 4;
    const size_t grow = (size_t)bt * 64 + row;

    float M = -__builtin_inff();
#pragma unroll
    for (int s = 0; s < 4; s++)
        if (s < nsplit) M = fmaxf(M, pML[(size_t)s * 32768 + grow][0]);

    float wgt0 = 0.f, wgt1 = 0.f, wgt2 = 0.f, wgt3 = 0.f;
    float W = 0.f;
    {
        f32x2 ml;
        ml = pML[grow];                        wgt0 = __expf(ml[0] - M); W += wgt0 * ml[1];
        if (nsplit > 1) { ml = pML[32768 + grow];          wgt1 = __expf(ml[0] - M); W += wgt1 * ml[1]; }
        if (nsplit > 2) { ml = pML[2 * 32768 + grow];      wgt2 = __expf(ml[0] - M); W += wgt2 * ml[1]; }
        if (nsplit > 3) { ml = pML[3 * 32768 + grow];      wgt3 = __expf(ml[0] - M); W += wgt3 * ml[1]; }
    }
    float inv = 1.f / W;

#pragma unroll
    for (int ff = 0; ff < 16; ff += 4) {
        f32x4 acc = zero4();
        acc += wgt0 * *(const f32x4*)(pO + grow * 64 + fb + ff);
        if (nsplit > 1) acc += wgt1 * *(const f32x4*)(pO + ((size_t)32768 + grow) * 64 + fb + ff);
        if (nsplit > 2) acc += wgt2 * *(const f32x4*)(pO + ((size_t)2 * 32768 + grow) * 64 + fb + ff);
        if (nsplit > 3) acc += wgt3 * *(const f32x4*)(pO + ((size_t)3 * 32768 + grow) * 64 + fb + ff);
        *(f32x4*)(out + grow * 64 + fb + ff) = acc * inv;
    }
}

// ---------------------------------------------------------------------------
extern "C" void kernel_launch(void* const* d_in, const int* in_sizes, int n_in,
                              void* d_out, int out_size, void* d_ws, size_t ws_size,
                              hipStream_t stream) {
    (void)in_sizes; (void)n_in; (void)out_size;
    const float* q_ = (const float*)d_in[0];
    const float* k_ = (const float*)d_in[1];
    const float* v_ = (const float*)d_in[2];
    const float* wq = (const float*)d_in[3];
    const float* bq = (const float*)d_in[4];
    const float* wk = (const float*)d_in[5];
    const float* bk = (const float*)d_in[6];
    const float* wv = (const float*)d_in[7];
    const float* bv = (const float*)d_in[8];

    const size_t PLANE = (size_t)8 * 4096 * 64;   // 2M elements (4 MB bf16)
    u16* qph = (u16*)d_ws;
    u16* qpl = qph + PLANE;
    u16* kph = qpl + PLANE;
    u16* kpl = kph + PLANE;
    u16* vp  = kpl + PLANE;
    const size_t planes_bytes = 5 * PLANE * sizeof(u16);          // 20 MB

    // adaptive j-split by available workspace
    auto fits = [&](int js) {
        size_t need = planes_bytes
                    + (size_t)js * 32768 * 64 * sizeof(float)     // partial O
                    + (size_t)js * 32768 * sizeof(f32x2);         // partial (m,l)
        return need <= ws_size;
    };
    int nsplit = fits(4) ? 4 : (fits(2) ? 2 : 1);

    float* pO  = (float*)((char*)d_ws + planes_bytes);
    f32x2* pML = (f32x2*)((char*)d_ws + planes_bytes
                          + (size_t)nsplit * 32768 * 64 * sizeof(float));

    proj_qkv_32727650796335<<<dim3(512, 3, 1), 256, 0, stream>>>(
        q_, k_, v_, wq, bq, wk, bk, wv, bv, qph, qpl, kph, kpl, vp);
    attn_fwd_32727650796335<<<dim3(64, 8, nsplit), 256, 0, stream>>>(
        qph, qpl, kph, kpl, vp, (float*)d_out, pO, pML, nsplit);
    if (nsplit > 1)
        combine_32727650796335<<<dim3(512, 1, 1), 256, 0, stream>>>(
            pO, pML, (float*)d_out, nsplit);
}

// Round 4
// 135.930 us; speedup vs baseline: 1.1899x; 1.1085x over previous
//
#include <hip/hip_runtime.h>

// ---------------------------------------------------------------------------
// DotProductAttention: out[b,i,f] = softmax_j(<K_i, Q_j>) @ V[j,f]
// Split-bf16 (hi+lo) scores; 32x32x16 MFMA; fragment-ordered LDS (0-conflict).
// B=8, L=4096, F=64.
// ---------------------------------------------------------------------------

typedef unsigned short u16;
typedef __attribute__((ext_vector_type(4))) unsigned int u32x4;
typedef __attribute__((ext_vector_type(4))) float f32x4;
typedef __attribute__((ext_vector_type(16))) float f32x16;
typedef __attribute__((ext_vector_type(2))) float f32x2;
typedef __attribute__((ext_vector_type(8))) short s16x8;

#define MFMA32(a, bb, c) __builtin_amdgcn_mfma_f32_32x32x16_bf16((a), (bb), (c), 0, 0, 0)
#define MFMA16(a, bb, c) __builtin_amdgcn_mfma_f32_16x16x32_bf16((a), (bb), (c), 0, 0, 0)

__device__ __forceinline__ short f2bf(float x) {
    unsigned u = __builtin_bit_cast(unsigned, x);
    u += 0x7fffu + ((u >> 16) & 1u);   // round-to-nearest-even
    return (short)(u >> 16);
}
__device__ __forceinline__ float bf2f(short h) {
    unsigned u = ((unsigned)(u16)h) << 16;
    return __builtin_bit_cast(float, u);
}
__device__ __forceinline__ f32x4 zero4() { f32x4 r = {0.f, 0.f, 0.f, 0.f}; return r; }

// split 8 fp32 values into hi/lo bf16 fragments
__device__ __forceinline__ void split8(f32x4 a, f32x4 b, s16x8& hi, s16x8& lo) {
#pragma unroll
    for (int i = 0; i < 4; i++) {
        short h = f2bf(a[i]);
        hi[i] = h;
        lo[i] = f2bf(a[i] - bf2f(h));
    }
#pragma unroll
    for (int i = 0; i < 4; i++) {
        short h = f2bf(b[i]);
        hi[i + 4] = h;
        lo[i + 4] = f2bf(b[i] - bf2f(h));
    }
}

// ---------------------------------------------------------------------------
// Projection kernel: Xp = X @ W^T + b, split-bf16 accurate, outputs
// FRAGMENT-ORDERED per 64-row chunk for the 32x32x16 attn kernel:
//   Q (hi+lo): idx = (row>>5)*2048 + (f>>4)*512 + ((row&31)+32*((f>>3)&1))*8 + (f&7)
//   K (hi+lo): plain row-major [32768][64]
//   V (bf16) : idx = (f>>5)*2048 + (row>>4)*512 + ((f&31)+32*((row>>2)&1))*8
//                    + ((row>>3)&1)*4 + (row&3)
// grid (512, 3), block 256.
// ---------------------------------------------------------------------------
__global__ __launch_bounds__(256) void proj_qkv_32727650796335(
    const float* __restrict__ q_, const float* __restrict__ k_, const float* __restrict__ v_,
    const float* __restrict__ wq, const float* __restrict__ bq,
    const float* __restrict__ wk, const float* __restrict__ bk,
    const float* __restrict__ wv, const float* __restrict__ bv,
    u16* __restrict__ qph, u16* __restrict__ qpl,
    u16* __restrict__ kph, u16* __restrict__ kpl,
    u16* __restrict__ vp) {
    const int z = blockIdx.y;
    const float* X  = (z == 0) ? q_ : (z == 1) ? k_ : v_;
    const float* W  = (z == 0) ? wq : (z == 1) ? wk : wv;
    const float* bi = (z == 0) ? bq : (z == 1) ? bk : bv;

    const int t = threadIdx.x;
    const int w = t >> 6, ln = t & 63, g = ln >> 4, lq = ln & 15;
    const int cidx = blockIdx.x;                 // 0..511 (b*64 + chunk)

    __shared__ f32x4 ldsX[1024];                 // 64 rows x 16 float4, swizzled

    const f32x4* X4 = (const f32x4*)X + (size_t)cidx * 1024;
#pragma unroll
    for (int kk = 0; kk < 4; kk++) {
        int lin = t + 256 * kk;
        int r = lin >> 4, c4 = lin & 15;
        ldsX[r * 16 + (c4 ^ (r & 7))] = X4[lin];
    }
    __syncthreads();

    float bv4[4];
#pragma unroll
    for (int nt = 0; nt < 4; nt++) bv4[nt] = bi[lq + 16 * nt];

    const f32x4* W4 = (const f32x4*)W;
    s16x8 wfh[4][2], wfl[4][2];
#pragma unroll
    for (int nt = 0; nt < 4; nt++)
#pragma unroll
        for (int kb = 0; kb < 2; kb++) {
            f32x4 a = W4[(lq + 16 * nt) * 16 + (g + 8 * kb)];
            f32x4 b = W4[(lq + 16 * nt) * 16 + (g + 4 + 8 * kb)];
            split8(a, b, wfh[nt][kb], wfl[nt][kb]);
        }

    s16x8 afh[2], afl[2];
#pragma unroll
    for (int kb = 0; kb < 2; kb++) {
        f32x4 a = ldsX[(16 * w + lq) * 16 + ((g + 8 * kb) ^ (lq & 7))];
        f32x4 b = ldsX[(16 * w + lq) * 16 + ((g + 4 + 8 * kb) ^ (lq & 7))];
        split8(a, b, afh[kb], afl[kb]);
    }

    f32x4 acc[4];
#pragma unroll
    for (int nt = 0; nt < 4; nt++) acc[nt] = zero4();
#pragma unroll
    for (int kb = 0; kb < 2; kb++)
#pragma unroll
        for (int nt = 0; nt < 4; nt++) {
            acc[nt] = MFMA16(afh[kb], wfh[nt][kb], acc[nt]);
            acc[nt] = MFMA16(afh[kb], wfl[nt][kb], acc[nt]);
            acc[nt] = MFMA16(afl[kb], wfh[nt][kb], acc[nt]);
        }

    // D: row_local = 16w + 4g + r, col f = lq + 16nt  (C/D layout, m89/m91)
#pragma unroll
    for (int nt = 0; nt < 4; nt++)
#pragma unroll
        for (int r = 0; r < 4; r++) {
            float val = acc[nt][r] + bv4[nt];
            short hi = f2bf(val);
            short lo = f2bf(val - bf2f(hi));
            int row = 16 * w + 4 * g + r;
            int f = lq + 16 * nt;
            if (z == 1) {
                size_t idx = ((size_t)cidx * 64 + row) * 64 + f;
                kph[idx] = (u16)hi;
                kpl[idx] = (u16)lo;
            } else if (z == 0) {
                // Q fragment order: A operand of 32x32x16 QK^T
                unsigned idx = (unsigned)((row >> 5) * 2048 + nt * 512
                             + ((row & 31) + ((lq >> 3) & 1) * 32) * 8 + (lq & 7));
                size_t o = (size_t)cidx * 4096 + idx;
                qph[o] = (u16)hi;
                qpl[o] = (u16)lo;
            } else {
                // V fragment order: A operand of 32x32x16 PV (V^T), j-map
                // j = 32*t2 + 16*qh + 8*(e>>2) + 4*h + (e&3), s4 = 2*t2+qh = row>>4
                unsigned idx = (unsigned)((f >> 5) * 2048 + (row >> 4) * 512
                             + ((f & 31) + ((row >> 2) & 1) * 32) * 8
                             + ((row >> 3) & 1) * 4 + (row & 3));
                vp[(size_t)cidx * 4096 + idx] = (u16)hi;
            }
        }
}

// ---------------------------------------------------------------------------
// Attention kernel. grid (32 itiles, 8 batches, nsplit). block 256 (4 waves).
// Wave w owns i-strip [itile*128 + 32w, +32); lane: i = ln&31, h = ln>>5.
// S^T tiles 32x32 (t2 = j-half); C/D: col=i=ln&31, row=(reg&3)+8*(reg>>2)+4h.
// P regs [8qh..8qh+7] ARE the PV B-fragment for slice s4=2*t2+qh (no shuffles).
// ---------------------------------------------------------------------------
__global__ __launch_bounds__(256, 3) void attn_fwd_32727650796335(
    const u16* __restrict__ qph, const u16* __restrict__ qpl,
    const u16* __restrict__ kph, const u16* __restrict__ kpl,
    const u16* __restrict__ vp, float* __restrict__ out,
    float* __restrict__ pO, f32x2* __restrict__ pML, int nsplit) {
    const int t = threadIdx.x;
    const int w = t >> 6, ln = t & 63, i5 = ln & 31, h = ln >> 5;
    const int itile = blockIdx.x, b = blockIdx.y, split = blockIdx.z;
    const int nc = 64 / nsplit;
    const int c0 = split * nc;

    __shared__ u32x4 ldsbuf[1536];               // Qhi [0,8K), Qlo [8K,16K), V [16K,24K)
    const char* ldsc = (const char*)ldsbuf;

    // K fragments (B operand): lane holds col i; k = 16ks + 8h + e
    const int irow = b * 4096 + itile * 128 + 32 * w + i5;   // global LK row
    const u16* krh = kph + (size_t)irow * 64;
    const u16* krl = kpl + (size_t)irow * 64;
    s16x8 kfh[4], kfl[4];
#pragma unroll
    for (int ks = 0; ks < 4; ks++) {
        kfh[ks] = *(const s16x8*)(krh + 16 * ks + 8 * h);
        kfl[ks] = *(const s16x8*)(krl + 16 * ks + 8 * h);
    }

    f32x16 oacc0 = {}, oacc1 = {};
    float m = -__builtin_inff();
    float lsum = 0.f;

    const u32x4* qsrcH = (const u32x4*)(qph + (size_t)(b * 64) * 4096);
    const u32x4* qsrcL = (const u32x4*)(qpl + (size_t)(b * 64) * 4096);
    const u32x4* vsrc  = (const u32x4*)(vp  + (size_t)(b * 64) * 4096);

    u32x4 qha, qhb, qla, qlb, va, vb;
#define LOADC(c) do { size_t o_ = (size_t)(c) * 512 + t;      \
        qha = qsrcH[o_]; qhb = qsrcH[o_ + 256];               \
        qla = qsrcL[o_]; qlb = qsrcL[o_ + 256];               \
        va  = vsrc[o_];  vb  = vsrc[o_ + 256]; } while (0)

    LOADC(c0);
    for (int cc = 0; cc < nc; cc++) {
        __syncthreads();                          // prev iter done reading LDS
        ldsbuf[t] = qha;
        ldsbuf[t + 256] = qhb;
        ldsbuf[t + 512] = qla;
        ldsbuf[t + 768] = qlb;
        ldsbuf[t + 1024] = va;
        ldsbuf[t + 1280] = vb;
        __syncthreads();
        if (cc + 1 < nc) LOADC(c0 + cc + 1);      // T14: issue next loads early

        // ---- QK^T : S^T 32x32 tiles t2=0,1 ; K=64 in 4 slices; split-bf16 ----
        f32x16 s0 = {}, s1 = {};
#pragma unroll
        for (int ks = 0; ks < 4; ks++) {
            const int fo = ks * 1024 + ln * 16;
            s16x8 qh0 = *(const s16x8*)(ldsc + fo);
            s16x8 qh1 = *(const s16x8*)(ldsc + 4096 + fo);
            s16x8 ql0 = *(const s16x8*)(ldsc + 8192 + fo);
            s16x8 ql1 = *(const s16x8*)(ldsc + 12288 + fo);
            s0 = MFMA32(qh0, kfh[ks], s0);
            s1 = MFMA32(qh1, kfh[ks], s1);
            s0 = MFMA32(qh0, kfl[ks], s0);
            s1 = MFMA32(qh1, kfl[ks], s1);
            s0 = MFMA32(ql0, kfh[ks], s0);
            s1 = MFMA32(ql1, kfh[ks], s1);
        }

        // ---- online softmax over j (32 in-lane + partner lane^32) ----
        float pmax = s0[0];
#pragma unroll
        for (int r = 1; r < 16; r++) pmax = fmaxf(pmax, s0[r]);
#pragma unroll
        for (int r = 0; r < 16; r++) pmax = fmaxf(pmax, s1[r]);
        pmax = fmaxf(pmax, __shfl_xor(pmax, 32));
        if (!__all(pmax <= m)) {                  // T13: skip rescale
            float mnew = fmaxf(m, pmax);
            float corr = __expf(m - mnew);        // first chunk: exp(-inf)=0
            lsum *= corr;
#pragma unroll
            for (int r = 0; r < 16; r++) { oacc0[r] *= corr; oacc1[r] *= corr; }
            m = mnew;
        }

        float p0[16], p1[16];
        float psum = 0.f;
#pragma unroll
        for (int r = 0; r < 16; r++) {
            p0[r] = __expf(s0[r] - m);
            p1[r] = __expf(s1[r] - m);
            psum += p0[r] + p1[r];
        }
        psum += __shfl_xor(psum, 32);
        lsum += psum;

        s16x8 pf[4];
#pragma unroll
        for (int qh = 0; qh < 2; qh++)
#pragma unroll
            for (int e = 0; e < 8; e++) {
                pf[qh][e]     = f2bf(p0[8 * qh + e]);
                pf[2 + qh][e] = f2bf(p1[8 * qh + e]);
            }

        // ---- PV : O^T[f,i] += V^T @ P^T  (fragment-ordered V, linear reads) ----
#pragma unroll
        for (int s4 = 0; s4 < 4; s4++) {
            s16x8 vf0 = *(const s16x8*)(ldsc + 16384 + s4 * 1024 + ln * 16);
            s16x8 vf1 = *(const s16x8*)(ldsc + 16384 + 4096 + s4 * 1024 + ln * 16);
            oacc0 = MFMA32(vf0, pf[s4], oacc0);
            oacc1 = MFMA32(vf1, pf[s4], oacc1);
        }
    }
#undef LOADC

    // ---- epilogue: f = 32*ft2 + 8*q + 4*h + r ; i = i5 ----
    if (nsplit == 1) {
        float inv = 1.f / lsum;
#pragma unroll
        for (int q = 0; q < 4; q++) {
            f32x4 o0, o1;
#pragma unroll
            for (int r = 0; r < 4; r++) { o0[r] = oacc0[4 * q + r] * inv; o1[r] = oacc1[4 * q + r] * inv; }
            *(f32x4*)(out + (size_t)irow * 64 + 8 * q + 4 * h) = o0;
            *(f32x4*)(out + (size_t)irow * 64 + 32 + 8 * q + 4 * h) = o1;
        }
    } else {
        size_t base = ((size_t)split * 32768 + (size_t)irow) * 64;
#pragma unroll
        for (int q = 0; q < 4; q++) {
            f32x4 o0, o1;
#pragma unroll
            for (int r = 0; r < 4; r++) { o0[r] = oacc0[4 * q + r]; o1[r] = oacc1[4 * q + r]; }
            *(f32x4*)(pO + base + 8 * q + 4 * h) = o0;
            *(f32x4*)(pO + base + 32 + 8 * q + 4 * h) = o1;
        }
        if (ln < 32) {
            f32x2 ml; ml[0] = m; ml[1] = lsum;
            pML[(size_t)split * 32768 + irow] = ml;
        }
    }
}

// ---------------------------------------------------------------------------
// Combine kernel: merge nsplit partials. grid 512, block 256.
// ---------------------------------------------------------------------------
__global__ __launch_bounds__(256) void combine_32727650796335(
    const float* __restrict__ pO, const f32x2* __restrict__ pML,
    float* __restrict__ out, int nsplit) {
    const int bt = blockIdx.x;
    const int t = threadIdx.x;
    const int row = t >> 2, fb = (t & 3) << 4;
    const size_t grow = (size_t)bt * 64 + row;

    float M = -__builtin_inff();
#pragma unroll
    for (int s = 0; s < 4; s++)
        if (s < nsplit) M = fmaxf(M, pML[(size_t)s * 32768 + grow][0]);

    float wgt0 = 0.f, wgt1 = 0.f, wgt2 = 0.f, wgt3 = 0.f;
    float W = 0.f;
    {
        f32x2 ml;
        ml = pML[grow];                                    wgt0 = __expf(ml[0] - M); W += wgt0 * ml[1];
        if (nsplit > 1) { ml = pML[32768 + grow];          wgt1 = __expf(ml[0] - M); W += wgt1 * ml[1]; }
        if (nsplit > 2) { ml = pML[2 * 32768 + grow];      wgt2 = __expf(ml[0] - M); W += wgt2 * ml[1]; }
        if (nsplit > 3) { ml = pML[3 * 32768 + grow];      wgt3 = __expf(ml[0] - M); W += wgt3 * ml[1]; }
    }
    float inv = 1.f / W;

#pragma unroll
    for (int ff = 0; ff < 16; ff += 4) {
        f32x4 acc = zero4();
        acc += wgt0 * *(const f32x4*)(pO + grow * 64 + fb + ff);
        if (nsplit > 1) acc += wgt1 * *(const f32x4*)(pO + ((size_t)32768 + grow) * 64 + fb + ff);
        if (nsplit > 2) acc += wgt2 * *(const f32x4*)(pO + ((size_t)2 * 32768 + grow) * 64 + fb + ff);
        if (nsplit > 3) acc += wgt3 * *(const f32x4*)(pO + ((size_t)3 * 32768 + grow) * 64 + fb + ff);
        *(f32x4*)(out + grow * 64 + fb + ff) = acc * inv;
    }
}

// ---------------------------------------------------------------------------
extern "C" void kernel_launch(void* const* d_in, const int* in_sizes, int n_in,
                              void* d_out, int out_size, void* d_ws, size_t ws_size,
                              hipStream_t stream) {
    (void)in_sizes; (void)n_in; (void)out_size;
    const float* q_ = (const float*)d_in[0];
    const float* k_ = (const float*)d_in[1];
    const float* v_ = (const float*)d_in[2];
    const float* wq = (const float*)d_in[3];
    const float* bq = (const float*)d_in[4];
    const float* wk = (const float*)d_in[5];
    const float* bk = (const float*)d_in[6];
    const float* wv = (const float*)d_in[7];
    const float* bv = (const float*)d_in[8];

    const size_t PLANE = (size_t)8 * 4096 * 64;   // 2M elements (4 MB bf16)
    u16* qph = (u16*)d_ws;
    u16* qpl = qph + PLANE;
    u16* kph = qpl + PLANE;
    u16* kpl = kph + PLANE;
    u16* vp  = kpl + PLANE;
    const size_t planes_bytes = 5 * PLANE * sizeof(u16);          // 20 MB

    auto fits = [&](int js) {
        size_t need = planes_bytes
                    + (size_t)js * 32768 * 64 * sizeof(float)
                    + (size_t)js * 32768 * sizeof(f32x2);
        return need <= ws_size;
    };
    int nsplit = fits(4) ? 4 : (fits(2) ? 2 : 1);

    float* pO  = (float*)((char*)d_ws + planes_bytes);
    f32x2* pML = (f32x2*)((char*)d_ws + planes_bytes
                          + (size_t)nsplit * 32768 * 64 * sizeof(float));

    proj_qkv_32727650796335<<<dim3(512, 3, 1), 256, 0, stream>>>(
        q_, k_, v_, wq, bq, wk, bk, wv, bv, qph, qpl, kph, kpl, vp);
    attn_fwd_32727650796335<<<dim3(32, 8, nsplit), 256, 0, stream>>>(
        qph, qpl, kph, kpl, vp, (float*)d_out, pO, pML, nsplit);
    if (nsplit > 1)
        combine_32727650796335<<<dim3(512, 1, 1), 256, 0, stream>>>(
            pO, pML, (float*)d_out, nsplit);
}